// Round 5
// baseline (639.753 us; speedup 1.0000x reference)
//
#include <hip/hip_runtime.h>

// Problem constants (fixed by the reference)
#define N_IMG 8
#define C_CLS 19
#define H_DIM 512
#define W_DIM 1024
#define HW (H_DIM * W_DIM)              // 524288 pixels per image
#define HW4 (HW / 4)                    // 131072 float4 groups per channel
#define TOTAL_ELEMS (N_IMG * C_CLS * HW)
#define RATIO 0.2f

#define BT 256
#define BLOCKS_X (HW4 / BT)             // 512 blocks per image, exact cover
#define NROWS (N_IMG * C_CLS)           // 152 (n,c) rows of per-block partials

__device__ __forceinline__ float& f4c(float4& v, int k) {
    return reinterpret_cast<float*>(&v)[k];   // k is compile-time after unroll
}

// Pass 1 (compute core identical to round 4; ending changed):
// per-block partial q-sums and histograms are STORED (no atomics, no pre-zero)
// to Qp/Hp[152][512]. Pure function of input -> idempotent -> launched 4x this
// round purely to measure its duration via dur_us arithmetic:
//   dur ~= fill(193us) + 4*A' + pass2 + gaps   =>  A' = (dur - ~205)/4
__global__ __launch_bounds__(BT, 4) void iw_pass1(
    const float* __restrict__ in,   // (N, C, H, W)
    float* __restrict__ Qp,         // [NROWS][BLOCKS_X] per-block q partials
    int* __restrict__ Hp)           // [NROWS][BLOCKS_X] per-block hist partials
{
    const int n   = blockIdx.y;
    const int tid = threadIdx.x;
    const int i   = blockIdx.x * BT + tid;       // float4 index in plane
    const float4* base4 = reinterpret_cast<const float4*>(in + (size_t)n * C_CLS * HW);

    // 19 independent 16B/lane loads, all in flight together
    float4 x[C_CLS];
#pragma unroll
    for (int c = 0; c < C_CLS; ++c)
        x[c] = base4[(size_t)c * HW4 + i];

    int   am[4];
    float inv[4];
#pragma unroll
    for (int k = 0; k < 4; ++k) {
        // argmax (first index on ties, matching jnp.argmax) + max
        float m = f4c(x[0], k);
        int   a = 0;
#pragma unroll
        for (int c = 1; c < C_CLS; ++c) {
            float xc = f4c(x[c], k);
            if (xc > m) { m = xc; a = c; }
        }
        am[k] = a;
        // softmax denom; overwrite component k in place with e^2
        float S = 0.0f;
#pragma unroll
        for (int c = 0; c < C_CLS; ++c) {
            float e = __expf(f4c(x[c], k) - m);
            S += e;
            f4c(x[c], k) = e * e;
        }
        inv[k] = __builtin_amdgcn_rcpf(S * S);   // p_c^2 = e^2 * inv
    }

    __shared__ float qs[C_CLS][BT / 4 + 1];   // 19 x 65 floats = 4.9 KB
    __shared__ int   hs[4][C_CLS];

    // per-thread q_c = sum_k e2[c][k]*inv[k]; 2 DPP shuffles; park in LDS
#pragma unroll
    for (int c = 0; c < C_CLS; ++c) {
        float v = x[c].x * inv[0];
        v = fmaf(x[c].y, inv[1], v);
        v = fmaf(x[c].z, inv[2], v);
        v = fmaf(x[c].w, inv[3], v);
        v += __shfl_xor(v, 1, 64);
        v += __shfl_xor(v, 2, 64);
        if ((tid & 3) == 0) qs[c][tid >> 2] = v;
    }

    // histogram via wave ballot: transient scalar counts, no VGPR accumulators
    const int wave = tid >> 6, lane = tid & 63;
#pragma unroll
    for (int c = 0; c < C_CLS; ++c) {
        int cnt = (int)__popcll(__ballot(am[0] == c))
                + (int)__popcll(__ballot(am[1] == c))
                + (int)__popcll(__ballot(am[2] == c))
                + (int)__popcll(__ballot(am[3] == c));
        if (lane == 0) hs[wave][c] = cnt;
    }
    __syncthreads();

    // 152 threads: class c = t>>3, slot s = t&7 sums 8 entries, then 3 shuffles
    if (tid < 8 * C_CLS) {
        const int c = tid >> 3, s = tid & 7;
        float v = 0.0f;
#pragma unroll
        for (int j = 0; j < 8; ++j) v += qs[c][s * 8 + j];
        v += __shfl_xor(v, 1, 64);
        v += __shfl_xor(v, 2, 64);
        v += __shfl_xor(v, 4, 64);
        if (s == 0) Qp[(n * C_CLS + c) * BLOCKS_X + blockIdx.x] = v;
    }
    if (tid < C_CLS) {
        int hv = hs[0][tid] + hs[1][tid] + hs[2][tid] + hs[3][tid];
        Hp[(n * C_CLS + tid) * BLOCKS_X + blockIdx.x] = hv;
    }
}

// Pass 2: single block. Reduce per-block partials, build weights, dot, write.
__global__ __launch_bounds__(512) void iw_pass2(
    const float* __restrict__ Qp,
    const int* __restrict__ Hp,
    float* __restrict__ out)
{
    const int t = threadIdx.x;
    __shared__ float h_l[NROWS];     // per-row hist (after ==0 -> 1)
    __shared__ float w_l[NROWS];     // per-row weight
    __shared__ float red[8];

    // Phase A: hist row sums (one thread per row)
    if (t < NROWS) {
        int hsum = 0;
        const int* row = Hp + (size_t)t * BLOCKS_X;
#pragma unroll 8
        for (int b = 0; b < BLOCKS_X; ++b) hsum += row[b];
        float v = (float)hsum;
        h_l[t] = (v == 0.0f) ? 1.0f : v;     // hist[hist==0] = 1
    }
    __syncthreads();

    // Phase B: weights w = (sum_c h / h)^RATIO per image
    if (t < NROWS) {
        const int n = t / C_CLS;
        float s = 0.0f;
#pragma unroll
        for (int c = 0; c < C_CLS; ++c) s += h_l[n * C_CLS + c];   // sum AFTER replacement
        w_l[t] = powf(s / h_l[t], RATIO);
    }
    __syncthreads();

    // Phase C: loss = sum over all rows/blocks of w[row] * Qp[row][b]
    float partial = 0.0f;
    for (int f = t; f < NROWS * BLOCKS_X; f += 512)
        partial = fmaf(w_l[f >> 9], Qp[f], partial);   // f>>9 == f / BLOCKS_X

    // block reduction: wave butterfly + cross-wave LDS
#pragma unroll
    for (int off = 32; off > 0; off >>= 1)
        partial += __shfl_xor(partial, off, 64);
    const int wave = t >> 6, lane = t & 63;
    if (lane == 0) red[wave] = partial;
    __syncthreads();
    if (t == 0) {
        float total = 0.0f;
#pragma unroll
        for (int w = 0; w < 8; ++w) total += red[w];
        out[0] = -total / (float)TOTAL_ELEMS;
    }
}

extern "C" void kernel_launch(void* const* d_in, const int* in_sizes, int n_in,
                              void* d_out, int out_size, void* d_ws, size_t ws_size,
                              hipStream_t stream)
{
    const float* in = (const float*)d_in[0];
    float* out = (float*)d_out;

    // workspace: Qp float[152*512] then Hp int[152*512]  (~622 KB total)
    float* Qp = (float*)d_ws;
    int*   Hp = (int*)((char*)d_ws + (size_t)NROWS * BLOCKS_X * sizeof(float));

    dim3 grid(BLOCKS_X, N_IMG);
    // Idempotent (pure stores) -> launch 4x to expose pass1 duration in dur_us.
    // A' = (dur_us - fill(~193) - ~12) / 4
    iw_pass1<<<grid, BT, 0, stream>>>(in, Qp, Hp);
    iw_pass1<<<grid, BT, 0, stream>>>(in, Qp, Hp);
    iw_pass1<<<grid, BT, 0, stream>>>(in, Qp, Hp);
    iw_pass1<<<grid, BT, 0, stream>>>(in, Qp, Hp);
    iw_pass2<<<1, 512, 0, stream>>>(Qp, Hp, out);
}